// Round 12
// baseline (488.122 us; speedup 1.0000x reference)
//
#include <hip/hip_runtime.h>
#include <math.h>

#define B    32
#define INF  784
#define H1   1024
#define H2   1024
#define NC   10
#define EPSV 0.1f
#define NBLK 768

typedef __attribute__((ext_vector_type(8))) short short8;
typedef __attribute__((ext_vector_type(4))) float floatx4;

__device__ inline ushort bf16_rne(float f) {
  uint u = __builtin_bit_cast(uint, f);
  u += 0x7FFFu + ((u >> 16) & 1u);
  return (ushort)(u >> 16);
}
__device__ inline uint pack2(float a, float b) {
  return (uint)bf16_rne(a) | ((uint)bf16_rne(b) << 16);
}
__device__ inline uint scale_pack(uint u, float d0, float d1v) {
  float f0 = __builtin_bit_cast(float, u << 16) * d0;
  float f1 = __builtin_bit_cast(float, u & 0xFFFF0000u) * d1v;
  uint r0 = __builtin_bit_cast(uint, f0) + 0x8000u;
  uint r1 = __builtin_bit_cast(uint, f1) + 0x8000u;
  return __builtin_amdgcn_perm(r1, r0, 0x07060302u);
}

// ---------------------------------------------------------------------------
// Grid barrier, generation g = 1,2,3,... (monotonic), ALL atomics RELAXED
// (r11: per-poll ACQUIRE cache-invalidates cost ~100us/barrier).
// r12 fix: 'gen' notification BROADCAST to 32 lines — r11 had 767 pollers on
// one line; its home L2 bank (~50-100 reads/us) made release-wake ~tens of us.
// Now <=24 pollers/line.  Fences once per block per barrier.
// ---------------------------------------------------------------------------
__device__ inline void grid_sync(uint* base, uint g) {
  __syncthreads();
  if (threadIdx.x == 0) {
    __threadfence();   // release (once)
    uint* ctr   = base + (blockIdx.x & 31) * 64;   // 32 arrival lines
    uint* done  = base + 32 * 64;                  // 1 line
    uint* gens  = base + 33 * 64;                  // 32 notification lines
    uint* mygen = gens + (blockIdx.x & 31) * 64;
    uint v = __hip_atomic_fetch_add(ctr, 1u, __ATOMIC_RELAXED, __HIP_MEMORY_SCOPE_AGENT) + 1u;
    if (v == g * 24u) {   // slice complete (768/32 = 24 per line)
      uint d = __hip_atomic_fetch_add(done, 1u, __ATOMIC_RELAXED, __HIP_MEMORY_SCOPE_AGENT) + 1u;
      if (d == g * 32u) {
#pragma unroll
        for (int i = 0; i < 32; i++)
          __hip_atomic_store(gens + i * 64, g, __ATOMIC_RELAXED, __HIP_MEMORY_SCOPE_AGENT);
      }
    }
    while (__hip_atomic_load(mygen, __ATOMIC_RELAXED, __HIP_MEMORY_SCOPE_AGENT) < g) {
      __builtin_amdgcn_s_sleep(8);
    }
    __threadfence();   // acquire (once)
  }
  __syncthreads();
}

#define K3_LOAD(c, A, Bv) do {                                                  \
  _Pragma("unroll")                                                             \
  for (int ni = 0; ni < 2; ni++)                                                \
    Bv[ni] = *reinterpret_cast<const uint4*>(bBase + (size_t)(c) * 32768 + ni * 512); \
  _Pragma("unroll")                                                             \
  for (int mi = 0; mi < 7; mi++)                                                \
    A[mi] = *reinterpret_cast<const uint4*>(aBase + (size_t)(c) * 25088 + mi * 512); \
} while (0)

#define K3F_COMP(c, A, Bv) do {                                                 \
  float4 dv0 = *reinterpret_cast<const float4*>(&sm.Ds[(c) * 32 + quad * 8]);   \
  float4 dv1 = *reinterpret_cast<const float4*>(&sm.Ds[(c) * 32 + quad * 8 + 4]);\
  short8 bfr[2];                                                                \
  _Pragma("unroll")                                                             \
  for (int ni = 0; ni < 2; ni++) {                                              \
    uint4 sb;                                                                   \
    sb.x = scale_pack(Bv[ni].x, dv0.x, dv0.y);                                  \
    sb.y = scale_pack(Bv[ni].y, dv0.z, dv0.w);                                  \
    sb.z = scale_pack(Bv[ni].z, dv1.x, dv1.y);                                  \
    sb.w = scale_pack(Bv[ni].w, dv1.z, dv1.w);                                  \
    bfr[ni] = __builtin_bit_cast(short8, sb);                                   \
  }                                                                             \
  _Pragma("unroll")                                                             \
  for (int mi = 0; mi < 7; mi++) {                                              \
    short8 af = __builtin_bit_cast(short8, A[mi]);                              \
    _Pragma("unroll")                                                           \
    for (int ni = 0; ni < 2; ni++)                                              \
      acc[mi][ni] = __builtin_amdgcn_mfma_f32_16x16x32_bf16(af, bfr[ni], acc[mi][ni], 0, 0, 0); \
  }                                                                             \
} while (0)

__global__ __launch_bounds__(256, 3) void k_mega(
    const float* __restrict__ x, const int* __restrict__ y,
    const float* __restrict__ W1, const float* __restrict__ b1,
    const float* __restrict__ W2, const float* __restrict__ b2,
    const float* __restrict__ W3, const float* __restrict__ b3,
    float* __restrict__ out, float* __restrict__ ws)
{
  float* d1B   = ws;
  float* t1B   = ws + 32768;
  float* dnB   = ws + 65536;
  float* Aar   = ws + 98304;    // 32768 (P1' matvec -> P2)
  float* ClA   = ws + 131072;   // 32768
  float* CuA   = ws + 163840;   // 32768
  float* E     = ws + 196608;   // 32768, zeroed in P0
  float* F     = ws + 229376;   // 1024, zeroed in P0
  float* F2    = ws + 230400;   // 20480, zeroed in P0
  float* nu2T  = ws + 328704;   // 393216
  ushort* W2F  = (ushort*)(ws + 721920);
  ushort* W1F  = (ushort*)(ws + 1246208);
  float* nu1fT = ws + 328704;   // overlay (after nu2T dead)
  float* hpart = ws + 721920;   // overlay (after W2F/W1F dead)
  float* ppart = ws + 721920;   // overlay (after hpart dead)
  uint* bar    = (uint*)(ws + 4000000);  // 65 lines, zeroed by hipMemsetAsync

  int bid = blockIdx.x;
  int t = threadIdx.x;
  int w = t >> 6, lane = t & 63;
  int quad = lane >> 4, l15 = lane & 15;

  __shared__ union {
    struct { float red[4][B + 1]; float Ts[4][32][17]; } p0;
    float Ds[H1];
    struct { float sd2[B], st2[B], sdb[B], swy[B], sw3[NC]; } p2;
    struct { float red[4][2 * NC]; } p4;
    struct { float red[4][NC]; } p6;
  } sm;

  // ================= P0: pack + layer-1 + zero-init (1487 virtual) ========
  for (int vb = bid; vb < 1487; vb += NBLK) {
    __syncthreads();
    if (vb < 64) {
      int jt = vb;
      for (int c = w; c < 32; c += 4) {
        const float* src = &W2[(size_t)(jt * 16 + l15) * H1 + c * 32 + quad * 8];
        float4 v0 = *reinterpret_cast<const float4*>(src);
        float4 v1 = *reinterpret_cast<const float4*>(src + 4);
        uint4 o;
        o.x = pack2(v0.x, v0.y); o.y = pack2(v0.z, v0.w);
        o.z = pack2(v1.x, v1.y); o.w = pack2(v1.z, v1.w);
        *reinterpret_cast<uint4*>(&W2F[((size_t)(c * 64 + jt) * 64 + lane) * 8]) = o;
      }
    } else if (vb < 456) {
      int idx = vb - 64;
      int mt = idx >> 3, cg = idx & 7;
      int c = cg * 4 + w;
      int col0 = mt * 16;
#pragma unroll
      for (int p = 0; p < 8; p++) {
        int r = p * 4 + (lane >> 4);
        sm.p0.Ts[w][r][lane & 15] = W1[(size_t)(c * 32 + r) * INF + col0 + (lane & 15)];
      }
      float f[8];
#pragma unroll
      for (int e = 0; e < 8; e++) f[e] = sm.p0.Ts[w][quad * 8 + e][l15];
      uint4 o;
      o.x = pack2(f[0], f[1]); o.y = pack2(f[2], f[3]);
      o.z = pack2(f[4], f[5]); o.w = pack2(f[6], f[7]);
      *reinterpret_cast<uint4*>(&W1F[((size_t)(c * 49 + mt) * 64 + lane) * 8]) = o;
    } else if (vb < 1480) {
      int i = vb - 456;
      const float* wr = W1 + (size_t)i * INF;
      float acc[B];
#pragma unroll
      for (int b = 0; b < B; b++) acc[b] = 0.f;
      float wabs = 0.f;
      for (int k = t; k < INF; k += 256) {
        float wv = wr[k];
        wabs += fabsf(wv);
#pragma unroll
        for (int b = 0; b < B; b++) acc[b] = fmaf(x[b * INF + k], wv, acc[b]);
      }
#pragma unroll
      for (int off = 32; off > 0; off >>= 1) {
#pragma unroll
        for (int b = 0; b < B; b++) acc[b] += __shfl_down(acc[b], off, 64);
        wabs += __shfl_down(wabs, off, 64);
      }
      if (lane == 0) {
#pragma unroll
        for (int b = 0; b < B; b++) sm.p0.red[w][b] = acc[b];
        sm.p0.red[w][B] = wabs;
      }
      __syncthreads();
      if (t < B) {
        float s = sm.p0.red[0][t] + sm.p0.red[1][t] + sm.p0.red[2][t] + sm.p0.red[3][t];
        float r = EPSV * (sm.p0.red[0][B] + sm.p0.red[1][B] + sm.p0.red[2][B] + sm.p0.red[3][B]);
        float nom = s + b1[i];
        float zl = nom - r, zu = nom + r;
        float d, l;
        if (zl >= 0.f)      { d = 1.f;            l = 0.f; }
        else if (zu > 0.f)  { d = zu / (zu - zl); l = zl;  }
        else                { d = 0.f;            l = 0.f; }
        d1B[(size_t)t * H1 + i] = d;
        t1B[(size_t)t * H1 + i] = d * l;
        dnB[(size_t)t * H1 + i] = d * nom;
      }
    } else {
      int zb = vb - 1480;
      for (int idx = t; idx < 8192; idx += 256) {
        int pos = zb * 8192 + idx;
        if (pos < 54272) E[pos] = 0.f;   // covers E, F, F2 (contiguous)
      }
    }
  }
  grid_sync(bar, 1u);

  // ===== P1': E-GEMM (1792 tiles) + k2 matvec (1024 tiles) as skew filler ==
  // Schedule: blocks 0..255: 3 GEMM; blocks 256..767: 2 GEMM + 2 matvec.
  for (int it = 0; it < 4; it++) {
    int gemm_vt = -1, mv_j = -1;
    if (it == 0)      gemm_vt = bid;
    else if (it == 1) gemm_vt = bid + 768;
    else if (it == 2) { if (bid < 256) gemm_vt = 1536 + bid; else mv_j = bid - 256; }
    else              { if (bid >= 256) mv_j = bid + 256; }

    if (gemm_vt >= 0) {
      int xg = gemm_vt % 7;
      int rem = gemm_vt / 7;
      int yg = rem & 7;
      int b = rem >> 3;
      int mt0 = xg * 7;
      int jt0 = yg * 8 + w * 2;

      __syncthreads();
      for (int idx = t; idx < H1; idx += 256) sm.Ds[idx] = d1B[(size_t)b * H1 + idx];
      __syncthreads();

      const ushort* aBase = W1F + ((size_t)mt0 * 64 + lane) * 8;
      const ushort* bBase = W2F + ((size_t)jt0 * 64 + lane) * 8;

      floatx4 acc[7][2];
#pragma unroll
      for (int mi = 0; mi < 7; mi++)
#pragma unroll
        for (int ni = 0; ni < 2; ni++) acc[mi][ni] = (floatx4){0.f, 0.f, 0.f, 0.f};

      uint4 a0[7], b0[2], a1[7], b1v[2];
      K3_LOAD(0, a0, b0);
      K3_LOAD(1, a1, b1v);
      for (int c = 0; c < 30; c += 2) {
        K3F_COMP(c, a0, b0);
        K3_LOAD(c + 2, a0, b0);
        K3F_COMP(c + 1, a1, b1v);
        if (c + 3 < 32) K3_LOAD(c + 3, a1, b1v);
      }
      K3F_COMP(30, a0, b0);
      K3F_COMP(31, a1, b1v);

#pragma unroll
      for (int ni = 0; ni < 2; ni++) {
        float s = 0.f;
#pragma unroll
        for (int mi = 0; mi < 7; mi++)
#pragma unroll
          for (int r = 0; r < 4; r++) s += fabsf(acc[mi][ni][r]);
        s += __shfl_xor(s, 16, 64);
        s += __shfl_xor(s, 32, 64);
        if (lane < 16) {
          int j = (jt0 + ni) * 16 + l15;
          atomicAdd(&E[(size_t)j * B + b], EPSV * s);
        }
      }
    } else if (mv_j >= 0) {
      int j = mv_j;
      int b0r = w * 8;
      float aA[8] = {}, aCl[8] = {}, aCu[8] = {};
      const float* __restrict__ w2r = W2 + (size_t)j * H1;
      for (int i = lane; i < H1; i += 64) {
        float wv = w2r[i];
        float wp = fmaxf(wv, 0.f), wn = fmaxf(-wv, 0.f);
#pragma unroll
        for (int r = 0; r < 8; r++) {
          float dv = dnB[(size_t)(b0r + r) * H1 + i];
          float tv = t1B[(size_t)(b0r + r) * H1 + i];
          aA[r]  = fmaf(wv, dv, aA[r]);
          aCl[r] = fmaf(wn, tv, aCl[r]);
          aCu[r] = fmaf(wp, tv, aCu[r]);
        }
      }
#pragma unroll
      for (int off = 32; off > 0; off >>= 1) {
#pragma unroll
        for (int r = 0; r < 8; r++) {
          aA[r]  += __shfl_down(aA[r],  off, 64);
          aCl[r] += __shfl_down(aCl[r], off, 64);
          aCu[r] += __shfl_down(aCu[r], off, 64);
        }
      }
      if (lane == 0) {
        float bj = b2[j];
#pragma unroll
        for (int r = 0; r < 8; r++) {
          Aar[(size_t)j * B + b0r + r] = aA[r] + bj;
          ClA[(size_t)j * B + b0r + r] = aCl[r];
          CuA[(size_t)j * B + b0r + r] = aCu[r];
        }
      }
    }
  }
  grid_sync(bar, 2u);

  // ================= P2': combine + nu2 build (1024 virtual, j = vb) ======
  for (int vb = bid; vb < 1024; vb += NBLK) {
    __syncthreads();
    int j = vb;
    if (t < B) {
      float a = Aar[(size_t)j * B + t], e = E[(size_t)j * B + t];
      float zl = a - e + ClA[(size_t)j * B + t];
      float zu = a + e - CuA[(size_t)j * B + t];
      float d, l;
      if (zl >= 0.f)      { d = 1.f;            l = 0.f; }
      else if (zu > 0.f)  { d = zu / (zu - zl); l = zl;  }
      else                { d = 0.f;            l = 0.f; }
      sm.p2.sd2[t] = d;
      sm.p2.st2[t] = d * l;
      sm.p2.sdb[t] = d * b2[j];
    }
    if (t >= 64 && t < 96)   sm.p2.swy[t - 64]  = W3[(size_t)y[t - 64] * H2 + j];
    if (t >= 128 && t < 138) sm.p2.sw3[t - 128] = W3[(size_t)(t - 128) * H2 + j];
    __syncthreads();
    for (int tt = t; tt < B * NC; tt += 256) {   // B*NC=320 > 256: strided
      int b = tt / NC, jc = tt - b * NC;
      float cw = sm.p2.swy[b] - sm.p2.sw3[jc];
      float d2v = sm.p2.sd2[b];
      nu2T[((size_t)b * H2 + j) * 12 + jc] = cw * d2v;
      float val = cw * sm.p2.sdb[b] + fmaxf(-cw, 0.f) * sm.p2.st2[b];
      atomicAdd(&F2[((size_t)(j & 63) * B + b) * NC + jc], val);
    }
  }
  grid_sync(bar, 3u);

  // ================= P3: k5b1 (512 virtual: x2, b32, s8) ==================
  for (int vb = bid; vb < 512; vb += NBLK) {
    int xg = vb & 1, b = (vb >> 1) & 31, s = vb >> 6;
    int i1 = xg * 512 + t * 2;
    const float* __restrict__ nrowb = nu2T + ((size_t)b * H2 + s * 128) * 12;
    const float* __restrict__ w2b = W2 + (size_t)s * 128 * H1 + i1;
    float h0[NC] = {}, h1[NC] = {};
    for (int i2 = 0; i2 < 128; i2++) {
      float2 wv = *reinterpret_cast<const float2*>(&w2b[(size_t)i2 * H1]);
      const float* __restrict__ nrow = nrowb + i2 * 12;
#pragma unroll
      for (int j = 0; j < NC; j++) {
        h0[j] = fmaf(nrow[j], wv.x, h0[j]);
        h1[j] = fmaf(nrow[j], wv.y, h1[j]);
      }
    }
#pragma unroll
    for (int j = 0; j < NC; j++) {
      float2 o; o.x = h0[j]; o.y = h1[j];
      *reinterpret_cast<float2*>(&hpart[(((size_t)s * B + b) * NC + j) * H1 + i1]) = o;
    }
  }
  grid_sync(bar, 4u);

  // ================= P4: k5b2 (128 virtual: x4, b32) ======================
  for (int vb = bid; vb < 128; vb += NBLK) {
    __syncthreads();
    int xg = vb & 3, b = vb >> 2;
    int i1 = xg * 256 + t;
    float d1v = d1B[(size_t)b * H1 + i1];
    float t1v = t1B[(size_t)b * H1 + i1];
    float dnv = dnB[(size_t)b * H1 + i1];
    float sn[NC], c1[NC];
#pragma unroll
    for (int j = 0; j < NC; j++) {
      float hv = 0.f;
#pragma unroll
      for (int s = 0; s < 8; s++)
        hv += hpart[(((size_t)s * B + b) * NC + j) * H1 + i1];
      nu1fT[((size_t)b * H1 + i1) * 12 + j] = hv * d1v;
      sn[j] = hv * dnv;
      c1[j] = fmaxf(-hv, 0.f) * t1v;
    }
#pragma unroll
    for (int off = 32; off > 0; off >>= 1) {
#pragma unroll
      for (int j = 0; j < NC; j++) {
        sn[j] += __shfl_down(sn[j], off, 64);
        c1[j] += __shfl_down(c1[j], off, 64);
      }
    }
    if (lane == 0) {
#pragma unroll
      for (int j = 0; j < NC; j++) { sm.p4.red[w][j] = sn[j]; sm.p4.red[w][NC + j] = c1[j]; }
    }
    __syncthreads();
    if (t < NC) {
      float s = 0.f;
      for (int ww = 0; ww < 4; ww++) s += sm.p4.red[ww][t] + sm.p4.red[ww][NC + t];
      atomicAdd(&F[b * NC + t], s);
    }
  }
  grid_sync(bar, 5u);

  // ================= P5: k5c1 (1024 virtual: kk4, b32, s8; 196 active) ====
  for (int vb = bid; vb < 1024; vb += NBLK) {
    int kk = vb & 3, b = (vb >> 2) & 31, s = vb >> 7;
    bool valid = (t < 196);
    int k = kk * 196 + (valid ? t : 0);
    const float* __restrict__ nrowb = nu1fT + ((size_t)b * H1 + s * 128) * 12;
    const float* __restrict__ w1b = W1 + (size_t)s * 128 * INF + k;
    float acc[NC] = {};
    for (int i1 = 0; i1 < 128; i1++) {
      float w1v = w1b[(size_t)i1 * INF];
      const float* __restrict__ nrow = nrowb + i1 * 12;
#pragma unroll
      for (int j = 0; j < NC; j++) acc[j] = fmaf(nrow[j], w1v, acc[j]);
    }
    if (valid) {
#pragma unroll
      for (int j = 0; j < NC; j++)
        ppart[(((size_t)s * B + b) * NC + j) * INF + k] = acc[j];
    }
  }
  grid_sync(bar, 6u);

  // ================= P6: k5c2 + out (32 virtual) ==========================
  for (int vb = bid; vb < 32; vb += NBLK) {
    __syncthreads();
    int b = vb;
    float e[NC] = {};
    for (int k = t; k < INF; k += 256) {
#pragma unroll
      for (int j = 0; j < NC; j++) {
        float v = 0.f;
#pragma unroll
        for (int s = 0; s < 8; s++)
          v += ppart[(((size_t)s * B + b) * NC + j) * INF + k];
        e[j] += fabsf(v);
      }
    }
#pragma unroll
    for (int off = 32; off > 0; off >>= 1) {
#pragma unroll
      for (int j = 0; j < NC; j++) e[j] += __shfl_down(e[j], off, 64);
    }
    if (lane == 0) {
#pragma unroll
      for (int j = 0; j < NC; j++) sm.p6.red[w][j] = e[j];
    }
    __syncthreads();
    if (t < NC) {
      float ef = 0.f;
      for (int ww = 0; ww < 4; ww++) ef += sm.p6.red[ww][t];
      float s = F[b * NC + t];
      for (int slot = 0; slot < 64; slot++)
        s += F2[((size_t)slot * B + b) * NC + t];
      int yb = y[b];
      s += b3[yb] - b3[t];
      out[b * NC + t] = EPSV * ef - s;
    }
  }
}

// ---------------------------------------------------------------------------
extern "C" void kernel_launch(void* const* d_in, const int* in_sizes, int n_in,
                              void* d_out, int out_size, void* d_ws, size_t ws_size,
                              hipStream_t stream) {
  const float* x  = (const float*)d_in[0];
  const int*   y  = (const int*)  d_in[1];
  const float* W1 = (const float*)d_in[2];
  const float* b1 = (const float*)d_in[3];
  const float* W2 = (const float*)d_in[4];
  const float* b2 = (const float*)d_in[5];
  const float* W3 = (const float*)d_in[6];
  const float* b3 = (const float*)d_in[7];
  float* out = (float*)d_out;
  float* ws  = (float*)d_ws;

  // barrier region: 65 x 256-B lines (32 ctr + 1 done + 32 gen) at byte
  // offset 16,000,000 (beyond all overlays).  Zeroed every launch.
  hipMemsetAsync((char*)d_ws + 16000000, 0, 16640, stream);
  k_mega<<<NBLK, 256, 0, stream>>>(x, y, W1, b1, W2, b2, W3, b3, out, ws);
}

// Round 13
// 235.824 us; speedup vs baseline: 2.0699x; 2.0699x over previous
//
#include <hip/hip_runtime.h>
#include <math.h>

#define B    32
#define INF  784
#define H1   1024
#define H2   1024
#define NC   10
#define EPSV 0.1f

typedef __attribute__((ext_vector_type(8))) short short8;
typedef __attribute__((ext_vector_type(4))) float floatx4;

__device__ inline ushort bf16_rne(float f) {
  uint u = __builtin_bit_cast(uint, f);
  u += 0x7FFFu + ((u >> 16) & 1u);
  return (ushort)(u >> 16);
}
__device__ inline uint pack2(float a, float b) {
  return (uint)bf16_rne(a) | ((uint)bf16_rne(b) << 16);
}
__device__ inline uint scale_pack(uint u, float d0, float d1v) {
  float f0 = __builtin_bit_cast(float, u << 16) * d0;
  float f1 = __builtin_bit_cast(float, u & 0xFFFF0000u) * d1v;
  uint r0 = __builtin_bit_cast(uint, f0) + 0x8000u;
  uint r1 = __builtin_bit_cast(uint, f1) + 0x8000u;
  return __builtin_amdgcn_perm(r1, r0, 0x07060302u);
}
// split packed bf16 pair v into relu(v) and relu(-v) (sign-cleared)
__device__ inline void relu_split(uint v, uint& p, uint& m) {
  uint sl = ((v >> 15) & 1u) - 1u;          // 0xFFFFFFFF if lo sign clear
  uint sh = ((v >> 31) & 1u) - 1u;          // 0xFFFFFFFF if hi sign clear
  uint keep = (sl & 0xFFFFu) | (sh & 0xFFFF0000u);
  p = v & keep;
  m = (v & ~keep) & 0x7FFF7FFFu;
}

// ---------------------------------------------------------------------------
// K_PRE (1207 blocks):
//  [0,64):      W2F pack   [16-dim = j, contraction = i]
//  [64,113):    W1F pack   [16-dim = k, contraction = i]   (49 tiles)
//  [113,177):   W2TF pack  [16-dim = i1, contraction = i2] (LDS transpose)
//  [177,1201):  layer-1 row i; writes d1B/t1B/dnB fp32 + dnF/t1F bf16 frags
//  [1201,1207): zero E/F/F2/Fef region (44544 floats from E base)
// ---------------------------------------------------------------------------
__global__ __launch_bounds__(256) void k_pre(
    const float* __restrict__ x, const float* __restrict__ W1,
    const float* __restrict__ b1, const float* __restrict__ W2,
    ushort* __restrict__ W1F, ushort* __restrict__ W2F,
    ushort* __restrict__ W2TF, ushort* __restrict__ dnF, ushort* __restrict__ t1F,
    float* __restrict__ d1B, float* __restrict__ t1B, float* __restrict__ dnB,
    float* __restrict__ Ezero)
{
  __shared__ float red[4][B + 1];
  __shared__ float Ts[4][32][17];
  int bid = blockIdx.x;
  int t = threadIdx.x;
  int w = t >> 6, lane = t & 63;
  int quad = lane >> 4, l15 = lane & 15;
  if (bid < 64) {
    int jt = bid;
    for (int c = w; c < 32; c += 4) {
      const float* src = &W2[(size_t)(jt * 16 + l15) * H1 + c * 32 + quad * 8];
      float4 v0 = *reinterpret_cast<const float4*>(src);
      float4 v1 = *reinterpret_cast<const float4*>(src + 4);
      uint4 o;
      o.x = pack2(v0.x, v0.y); o.y = pack2(v0.z, v0.w);
      o.z = pack2(v1.x, v1.y); o.w = pack2(v1.z, v1.w);
      *reinterpret_cast<uint4*>(&W2F[((size_t)(c * 64 + jt) * 64 + lane) * 8]) = o;
    }
  } else if (bid < 113) {
    int mt = bid - 64;
    int col0 = mt * 16;
    for (int cg = 0; cg < 8; cg++) {
      int c = cg * 4 + w;
#pragma unroll
      for (int p = 0; p < 8; p++) {
        int r = p * 4 + quad;
        Ts[w][r][l15] = W1[(size_t)(c * 32 + r) * INF + col0 + l15];
      }
      float f[8];
#pragma unroll
      for (int e = 0; e < 8; e++) f[e] = Ts[w][quad * 8 + e][l15];
      uint4 o;
      o.x = pack2(f[0], f[1]); o.y = pack2(f[2], f[3]);
      o.z = pack2(f[4], f[5]); o.w = pack2(f[6], f[7]);
      *reinterpret_cast<uint4*>(&W1F[((size_t)(c * 49 + mt) * 64 + lane) * 8]) = o;
    }
  } else if (bid < 177) {
    int it = bid - 113;
    int col0 = it * 16;
    for (int cg = 0; cg < 8; cg++) {
      int c = cg * 4 + w;
#pragma unroll
      for (int p = 0; p < 8; p++) {
        int r = p * 4 + quad;
        Ts[w][r][l15] = W2[(size_t)(c * 32 + r) * H1 + col0 + l15];
      }
      float f[8];
#pragma unroll
      for (int e = 0; e < 8; e++) f[e] = Ts[w][quad * 8 + e][l15];
      uint4 o;
      o.x = pack2(f[0], f[1]); o.y = pack2(f[2], f[3]);
      o.z = pack2(f[4], f[5]); o.w = pack2(f[6], f[7]);
      *reinterpret_cast<uint4*>(&W2TF[((size_t)(c * 64 + it) * 64 + lane) * 8]) = o;
    }
  } else if (bid < 1201) {
    int i = bid - 177;
    const float* wr = W1 + (size_t)i * INF;
    float acc[B];
#pragma unroll
    for (int b = 0; b < B; b++) acc[b] = 0.f;
    float wabs = 0.f;
    for (int k = t; k < INF; k += 256) {
      float wv = wr[k];
      wabs += fabsf(wv);
#pragma unroll
      for (int b = 0; b < B; b++) acc[b] = fmaf(x[b * INF + k], wv, acc[b]);
    }
#pragma unroll
    for (int off = 32; off > 0; off >>= 1) {
#pragma unroll
      for (int b = 0; b < B; b++) acc[b] += __shfl_down(acc[b], off, 64);
      wabs += __shfl_down(wabs, off, 64);
    }
    if (lane == 0) {
#pragma unroll
      for (int b = 0; b < B; b++) red[w][b] = acc[b];
      red[w][B] = wabs;
    }
    __syncthreads();
    if (t < B) {
      float s = red[0][t] + red[1][t] + red[2][t] + red[3][t];
      float r = EPSV * (red[0][B] + red[1][B] + red[2][B] + red[3][B]);
      float nom = s + b1[i];
      float zl = nom - r, zu = nom + r;
      float d, l;
      if (zl >= 0.f)      { d = 1.f;            l = 0.f; }
      else if (zu > 0.f)  { d = zu / (zu - zl); l = zl;  }
      else                { d = 0.f;            l = 0.f; }
      float dn = d * nom, t1 = d * l;
      d1B[(size_t)t * H1 + i] = d;
      t1B[(size_t)t * H1 + i] = t1;
      dnB[(size_t)t * H1 + i] = dn;
      // bf16 B-operand fragments [k=i][n=b]
      int c = i >> 5, bt = t >> 4;
      size_t fa = ((size_t)(c * 2 + bt) * 64 + ((t & 15) | (((i >> 3) & 3) << 4))) * 8 + (i & 7);
      dnF[fa] = bf16_rne(dn);
      t1F[fa] = bf16_rne(t1);
    }
  } else {
    int zb = bid - 1201;
    for (int idx = t; idx < 8192; idx += 256) {
      int pos = zb * 8192 + idx;
      if (pos < 44544) Ezero[pos] = 0.f;   // E, F, F2, Fef (contiguous)
    }
  }
}

// ---------------------------------------------------------------------------
// K3: unchanged r8 (78 us, in-loop d1 scaling).
// ---------------------------------------------------------------------------
#define K3_LOAD(c, A, Bv) do {                                                  \
  _Pragma("unroll")                                                             \
  for (int ni = 0; ni < 2; ni++)                                                \
    Bv[ni] = *reinterpret_cast<const uint4*>(bBase + (size_t)(c) * 32768 + ni * 512); \
  _Pragma("unroll")                                                             \
  for (int mi = 0; mi < 7; mi++)                                                \
    A[mi] = *reinterpret_cast<const uint4*>(aBase + (size_t)(c) * 25088 + mi * 512); \
} while (0)

#define K3F_COMP(c, A, Bv) do {                                                 \
  float4 dv0 = *reinterpret_cast<const float4*>(&Ds[(c) * 32 + quad * 8]);      \
  float4 dv1 = *reinterpret_cast<const float4*>(&Ds[(c) * 32 + quad * 8 + 4]);  \
  short8 bfr[2];                                                                \
  _Pragma("unroll")                                                             \
  for (int ni = 0; ni < 2; ni++) {                                              \
    uint4 sb;                                                                   \
    sb.x = scale_pack(Bv[ni].x, dv0.x, dv0.y);                                  \
    sb.y = scale_pack(Bv[ni].y, dv0.z, dv0.w);                                  \
    sb.z = scale_pack(Bv[ni].z, dv1.x, dv1.y);                                  \
    sb.w = scale_pack(Bv[ni].w, dv1.z, dv1.w);                                  \
    bfr[ni] = __builtin_bit_cast(short8, sb);                                   \
  }                                                                             \
  _Pragma("unroll")                                                             \
  for (int mi = 0; mi < 7; mi++) {                                              \
    short8 af = __builtin_bit_cast(short8, A[mi]);                              \
    _Pragma("unroll")                                                           \
    for (int ni = 0; ni < 2; ni++)                                              \
      acc[mi][ni] = __builtin_amdgcn_mfma_f32_16x16x32_bf16(af, bfr[ni], acc[mi][ni], 0, 0, 0); \
  }                                                                             \
} while (0)

__global__ __launch_bounds__(256, 3) void k3(
    const ushort* __restrict__ W1F, const ushort* __restrict__ W2F,
    const float* __restrict__ d1B, float* __restrict__ E)
{
  int b = blockIdx.z;
  int t = threadIdx.x, w = t >> 6, lane = t & 63;
  int quad = lane >> 4, l15 = lane & 15;
  int mt0 = blockIdx.x * 7;
  int jt0 = blockIdx.y * 8 + w * 2;

  __shared__ float Ds[H1];
  for (int idx = t; idx < H1; idx += 256) Ds[idx] = d1B[(size_t)b * H1 + idx];
  __syncthreads();

  const ushort* aBase = W1F + ((size_t)mt0 * 64 + lane) * 8;
  const ushort* bBase = W2F + ((size_t)jt0 * 64 + lane) * 8;

  floatx4 acc[7][2];
#pragma unroll
  for (int mi = 0; mi < 7; mi++)
#pragma unroll
    for (int ni = 0; ni < 2; ni++) acc[mi][ni] = (floatx4){0.f, 0.f, 0.f, 0.f};

  uint4 a0[7], b0[2], a1[7], b1v[2];
  K3_LOAD(0, a0, b0);
  K3_LOAD(1, a1, b1v);
  for (int c = 0; c < 30; c += 2) {
    K3F_COMP(c, a0, b0);
    K3_LOAD(c + 2, a0, b0);
    K3F_COMP(c + 1, a1, b1v);
    if (c + 3 < 32) K3_LOAD(c + 3, a1, b1v);
  }
  K3F_COMP(30, a0, b0);
  K3F_COMP(31, a1, b1v);

#pragma unroll
  for (int ni = 0; ni < 2; ni++) {
    float s = 0.f;
#pragma unroll
    for (int mi = 0; mi < 7; mi++)
#pragma unroll
      for (int r = 0; r < 4; r++) s += fabsf(acc[mi][ni][r]);
    s += __shfl_xor(s, 16, 64);
    s += __shfl_xor(s, 32, 64);
    if (lane < 16) {
      int j = (jt0 + ni) * 16 + l15;
      atomicAdd(&E[(size_t)j * B + b], EPSV * s);
    }
  }
}

// ---------------------------------------------------------------------------
// K24_MFMA: layer-2 matvecs as MFMA + combine + nu2F build.
// Per wave: mt = bid*4+w (one j-tile, all 32 b).  4 GEMMs: {W2+,W2-}x{dn,t1}.
// Epilogue: d2/t2/db2 in-register -> nu2F bf16 fragments + F2 atomics.
// grid 16 blocks.
// ---------------------------------------------------------------------------
__global__ __launch_bounds__(256) void k24_mfma(
    const ushort* __restrict__ W2F, const ushort* __restrict__ dnF,
    const ushort* __restrict__ t1F, const float* __restrict__ E,
    const float* __restrict__ b2, const float* __restrict__ W3,
    const int* __restrict__ y,
    ushort* __restrict__ nu2F, float* __restrict__ F2)
{
  int t = threadIdx.x, w = t >> 6, lane = t & 63;
  int quad = lane >> 4, l15 = lane & 15;
  int mt = blockIdx.x * 4 + w;   // 0..63
  int j0 = mt * 16;

  floatx4 accP[2], accQ[2], accU[2], accL[2];
#pragma unroll
  for (int bt = 0; bt < 2; bt++) {
    accP[bt] = (floatx4){0.f, 0.f, 0.f, 0.f}; accQ[bt] = accP[bt];
    accU[bt] = accP[bt]; accL[bt] = accP[bt];
  }
  const ushort* aBase = W2F + ((size_t)mt * 64 + lane) * 8;

  for (int c = 0; c < 32; c++) {
    uint4 av = *reinterpret_cast<const uint4*>(aBase + (size_t)c * 32768);
    uint4 ap, am;
    relu_split(av.x, ap.x, am.x);
    relu_split(av.y, ap.y, am.y);
    relu_split(av.z, ap.z, am.z);
    relu_split(av.w, ap.w, am.w);
    short8 afp = __builtin_bit_cast(short8, ap);
    short8 afm = __builtin_bit_cast(short8, am);
#pragma unroll
    for (int bt = 0; bt < 2; bt++) {
      uint4 bd = *reinterpret_cast<const uint4*>(dnF + ((size_t)(c * 2 + bt) * 64 + lane) * 8);
      uint4 bl = *reinterpret_cast<const uint4*>(t1F + ((size_t)(c * 2 + bt) * 64 + lane) * 8);
      short8 fbd = __builtin_bit_cast(short8, bd);
      short8 fbl = __builtin_bit_cast(short8, bl);
      accP[bt] = __builtin_amdgcn_mfma_f32_16x16x32_bf16(afp, fbd, accP[bt], 0, 0, 0);
      accQ[bt] = __builtin_amdgcn_mfma_f32_16x16x32_bf16(afm, fbd, accQ[bt], 0, 0, 0);
      accU[bt] = __builtin_amdgcn_mfma_f32_16x16x32_bf16(afp, fbl, accU[bt], 0, 0, 0);
      accL[bt] = __builtin_amdgcn_mfma_f32_16x16x32_bf16(afm, fbl, accL[bt], 0, 0, 0);
    }
  }

  // epilogue: lane holds (row j = j0+quad*4+r, col b = bt*16+l15)
  float wyr[4], w3r[NC][4];
#pragma unroll
  for (int r = 0; r < 4; r++) {
    int j = j0 + quad * 4 + r;
#pragma unroll
    for (int jc = 0; jc < NC; jc++) w3r[jc][r] = W3[(size_t)jc * H2 + j];
  }
  int laneHi = (((mt & 1) * 2 + (quad >> 1)) << 4);
  int eOff = (quad & 1) * 4;
#pragma unroll
  for (int bt = 0; bt < 2; bt++) {
    int b = bt * 16 + l15;
    int yb = y[b];
#pragma unroll
    for (int r = 0; r < 4; r++) {
      int j = j0 + quad * 4 + r;
      wyr[r] = W3[(size_t)yb * H2 + j];
    }
    float dd[4], tt2[4], ddb[4];
#pragma unroll
    for (int r = 0; r < 4; r++) {
      int j = j0 + quad * 4 + r;
      float bj = b2[j];
      float a = accP[bt][r] - accQ[bt][r] + bj;
      float e = E[(size_t)j * B + b];
      float zl = a - e + accL[bt][r];
      float zu = a + e - accU[bt][r];
      float d, l;
      if (zl >= 0.f)      { d = 1.f;            l = 0.f; }
      else if (zu > 0.f)  { d = zu / (zu - zl); l = zl;  }
      else                { d = 0.f;            l = 0.f; }
      dd[r] = d; tt2[r] = d * l; ddb[r] = d * bj;
    }
    ushort* nbase = nu2F + ((size_t)b * 32 + (mt >> 1)) * 512;
#pragma unroll
    for (int jc = 0; jc < 16; jc++) {
      ushort4 o;
      float fv = 0.f;
      if (jc < NC) {
        float nu[4];
#pragma unroll
        for (int r = 0; r < 4; r++) {
          float cw = wyr[r] - w3r[jc][r];
          nu[r] = cw * dd[r];
          fv += cw * ddb[r] + fmaxf(-cw, 0.f) * tt2[r];
        }
        o.x = bf16_rne(nu[0]); o.y = bf16_rne(nu[1]);
        o.z = bf16_rne(nu[2]); o.w = bf16_rne(nu[3]);
      } else {
        o.x = o.y = o.z = o.w = 0;
      }
      *reinterpret_cast<ushort4*>(nbase + (size_t)(jc | laneHi) * 8 + eOff) = o;
      if (jc < NC) {
        fv += __shfl_xor(fv, 16, 64);
        fv += __shfl_xor(fv, 32, 64);
        if (lane < 16) atomicAdd(&F2[((size_t)(mt & 31) * B + b) * NC + jc], fv);
      }
    }
  }
}

// ---------------------------------------------------------------------------
// K5B1_MFMA: h = W2^T x nu2 per b (M=i1, N=j(16), K=i2) + fused k5b2 epilogue.
// grid (4, 32); wave: 4 m-tiles, full K.  Writes nu1fF bf16 frags + F atomics.
// ---------------------------------------------------------------------------
__global__ __launch_bounds__(256) void k5b1_mfma(
    const ushort* __restrict__ W2TF, const ushort* __restrict__ nu2F,
    const float* __restrict__ d1B, const float* __restrict__ t1B,
    const float* __restrict__ dnB,
    ushort* __restrict__ nu1fF, float* __restrict__ F)
{
  int t = threadIdx.x, w = t >> 6, lane = t & 63;
  int quad = lane >> 4, l15 = lane & 15;
  int b = blockIdx.y;
  int mt0 = blockIdx.x * 16 + w * 4;

  floatx4 acc[4];
#pragma unroll
  for (int mt = 0; mt < 4; mt++) acc[mt] = (floatx4){0.f, 0.f, 0.f, 0.f};

  for (int c = 0; c < 32; c++) {
    uint4 bv = *reinterpret_cast<const uint4*>(nu2F + ((size_t)(b * 32 + c)) * 512 + lane * 8);
    short8 bf = __builtin_bit_cast(short8, bv);
#pragma unroll
    for (int mt = 0; mt < 4; mt++) {
      uint4 av = *reinterpret_cast<const uint4*>(W2TF + ((size_t)(c * 64 + mt0 + mt)) * 512 + lane * 8);
      acc[mt] = __builtin_amdgcn_mfma_f32_16x16x32_bf16(
          __builtin_bit_cast(short8, av), bf, acc[mt], 0, 0, 0);
    }
  }

  // lane holds (row i1 = M*16+quad*4+r, col j = l15)
  float fs = 0.f;
#pragma unroll
  for (int mt = 0; mt < 4; mt++) {
    int M = mt0 + mt;
    int i1b = M * 16 + quad * 4;
    ushort4 o;
#pragma unroll
    for (int r = 0; r < 4; r++) {
      int i1 = i1b + r;
      float hv = acc[mt][r];
      float nu = hv * d1B[(size_t)b * H1 + i1];
      ((ushort*)&o)[r] = bf16_rne(nu);
      fs += hv * dnB[(size_t)b * H1 + i1] + fmaxf(-hv, 0.f) * t1B[(size_t)b * H1 + i1];
    }
    int laneHi = (((M & 1) * 2 + (quad >> 1)) << 4);
    *reinterpret_cast<ushort4*>(nu1fF + ((size_t)b * 32 + (M >> 1)) * 512 +
                                (size_t)(l15 | laneHi) * 8 + (quad & 1) * 4) = o;
  }
  fs += __shfl_xor(fs, 16, 64);
  fs += __shfl_xor(fs, 32, 64);
  if (lane < 16 && l15 < NC) atomicAdd(&F[b * NC + l15], fs);
}

// ---------------------------------------------------------------------------
// K5C1_MFMA: p = W1 x nu1f per b (M=k 49 tiles, N=j, K=i1) + fused |p|-reduce.
// grid (13, 32); wave mt = bx*4+w (guard <49), full K.  Fef atomics.
// ---------------------------------------------------------------------------
__global__ __launch_bounds__(256) void k5c1_mfma(
    const ushort* __restrict__ W1F, const ushort* __restrict__ nu1fF,
    float* __restrict__ Fef)
{
  int t = threadIdx.x, w = t >> 6, lane = t & 63;
  int l15 = lane & 15;
  int b = blockIdx.y;
  int mt = blockIdx.x * 4 + w;
  if (mt >= 49) return;

  floatx4 acc = (floatx4){0.f, 0.f, 0.f, 0.f};
  for (int c = 0; c < 32; c++) {
    uint4 av = *reinterpret_cast<const uint4*>(W1F + ((size_t)(c * 49 + mt) * 64 + lane) * 8);
    uint4 bv = *reinterpret_cast<const uint4*>(nu1fF + ((size_t)(b * 32 + c)) * 512 + lane * 8);
    acc = __builtin_amdgcn_mfma_f32_16x16x32_bf16(
        __builtin_bit_cast(short8, av), __builtin_bit_cast(short8, bv), acc, 0, 0, 0);
  }
  float s = fabsf(acc[0]) + fabsf(acc[1]) + fabsf(acc[2]) + fabsf(acc[3]);
  s += __shfl_xor(s, 16, 64);
  s += __shfl_xor(s, 32, 64);
  if (lane < 16 && l15 < NC) atomicAdd(&Fef[b * 16 + l15], s);
}

// ---------------------------------------------------------------------------
// K_OUT: out = EPSV*Fef - (F + sum_slots F2 + b3[yb] - b3[jc])
// ---------------------------------------------------------------------------
__global__ __launch_bounds__(512) void k_out(
    const float* __restrict__ F, const float* __restrict__ F2,
    const float* __restrict__ Fef, const float* __restrict__ b3,
    const int* __restrict__ y, float* __restrict__ out)
{
  int idx = threadIdx.x;
  if (idx < B * NC) {
    int b = idx / NC, jc = idx - b * NC;
    float s = F[b * NC + jc];
    for (int slot = 0; slot < 32; slot++)
      s += F2[((size_t)slot * B + b) * NC + jc];
    s += b3[y[b]] - b3[jc];
    out[idx] = EPSV * Fef[b * 16 + jc] - s;
  }
}

// ---------------------------------------------------------------------------
extern "C" void kernel_launch(void* const* d_in, const int* in_sizes, int n_in,
                              void* d_out, int out_size, void* d_ws, size_t ws_size,
                              hipStream_t stream) {
  const float* x  = (const float*)d_in[0];
  const int*   y  = (const int*)  d_in[1];
  const float* W1 = (const float*)d_in[2];
  const float* b1 = (const float*)d_in[3];
  const float* W2 = (const float*)d_in[4];
  const float* b2 = (const float*)d_in[5];
  const float* W3 = (const float*)d_in[6];
  const float* b3 = (const float*)d_in[7];
  float* out = (float*)d_out;
  float* ws  = (float*)d_ws;

  // ---- workspace layout (floats) — no overlays, all live regions disjoint --
  float* d1B   = ws;             // 32768
  float* t1B   = ws + 32768;
  float* dnB   = ws + 65536;
  float* E     = ws + 98304;     // 32768  ┐ zero region
  float* F     = ws + 131072;    // 1024   │ 44544 floats
  float* F2    = ws + 132096;    // 10240  │ (zeroed in k_pre)
  float* Fef   = ws + 142336;    // 512    ┘
  ushort* W2F   = (ushort*)(ws + 150000);   // 1048576 us
  ushort* W1F   = (ushort*)(ws + 674288);   // 802816 us
  ushort* W2TF  = (ushort*)(ws + 1075696);  // 1048576 us
  ushort* dnF   = (ushort*)(ws + 1599984);  // 32768 us
  ushort* t1F   = (ushort*)(ws + 1616368);  // 32768 us
  ushort* nu2F  = (ushort*)(ws + 1632752);  // 524288 us
  ushort* nu1fF = (ushort*)(ws + 1894896);  // 524288 us (end ~8.6 MB)

  k_pre<<<1207, 256, 0, stream>>>(x, W1, b1, W2, W1F, W2F, W2TF, dnF, t1F,
                                  d1B, t1B, dnB, E);
  k3<<<dim3(7, 8, 32), 256, 0, stream>>>(W1F, W2F, d1B, E);
  k24_mfma<<<16, 256, 0, stream>>>(W2F, dnF, t1F, E, b2, W3, y, nu2F, F2);
  k5b1_mfma<<<dim3(4, B), 256, 0, stream>>>(W2TF, nu2F, d1B, t1B, dnB, nu1fF, F);
  k5c1_mfma<<<dim3(13, B), 256, 0, stream>>>(W1F, nu1fF, Fef);
  k_out<<<1, 512, 0, stream>>>(F, F2, Fef, b3, y, out);
}